// Round 4
// baseline (159.908 us; speedup 1.0000x reference)
//
#include <hip/hip_runtime.h>
#include <hip/hip_cooperative_groups.h>
#include <math.h>

namespace cg = cooperative_groups;

#define BB 32
#define LL 128
#define DD 256
#define HH 1024   // 4*D

__device__ __forceinline__ float waveReduceSum(float v) {
#pragma unroll
    for (int m = 32; m >= 1; m >>= 1) v += __shfl_xor(v, m, 64);
    return v;
}
__device__ __forceinline__ float waveReduceMax(float v) {
#pragma unroll
    for (int m = 32; m >= 1; m >>= 1) v = fmaxf(v, __shfl_xor(v, m, 64));
    return v;
}

__device__ __forceinline__ float masked_we(float w) {
    return (fabsf(w) < 1e-7f) ? -1e7f : w;
}

// One cooperative kernel, 256 blocks x 256 threads.
// Block (b = blk>>3, g = blk&7) owns 16 rows of a1 and 16 rows of a2 of batch b,
// cached in LDS across phases (a1/a2 read from HBM exactly once).
__global__ __launch_bounds__(256) void fused_all(
    const float* __restrict__ a1, const int* __restrict__ len1,
    const float* __restrict__ a2, const int* __restrict__ len2,
    const float* __restrict__ fcw, const float* __restrict__ fcb,
    const float* __restrict__ ww, float* __restrict__ out,
    float* __restrict__ wsS, float* __restrict__ wsRC, float* __restrict__ wsPp)
{
    cg::grid_group grid = cg::this_grid();
    const int blk  = blockIdx.x;   // 0..255
    const int b    = blk >> 3;     // batch 0..31
    const int g    = blk & 7;      // row-group 0..7
    const int tid  = threadIdx.x;
    const int wave = tid >> 6;
    const int lane = tid & 63;

    __shared__ __align__(16) float4 wws4[DD / 4];
    __shared__ __align__(16) float4 A1l4[16][DD / 4];   // 16 KB
    __shared__ __align__(16) float4 A2l4[16][DD / 4];   // 16 KB
    __shared__ float s1[LL], s2[LL], rs[LL], cs[LL], part[256];
    __shared__ float redM[4], redS[4];
    __shared__ float gmax_s, dinv_s;
    __shared__ float rc1[16], rc2[16];
    __shared__ __align__(16) float ps[DD];

    if (tid < DD / 4) wws4[tid] = ((const float4*)ww)[tid];
    __syncthreads();

    // ---- phase 1: s-dots for this block's 32 rows; rows cached into LDS ----
    {
        const int k = tid >> 4;        // local row 0..15
        const int t = tid & 15;        // 16 threads per row
        const size_t rowoff = ((size_t)b * LL + g * 16 + k) * DD;
        const float4* __restrict__ r1 = (const float4*)(a1 + rowoff);
        const float4* __restrict__ r2 = (const float4*)(a2 + rowoff);
        float d1 = 0.f, d2 = 0.f;
#pragma unroll
        for (int q = 0; q < 4; ++q) {
            const int idx = t + 16 * q;
            const float4 w  = wws4[idx];
            const float4 v1 = r1[idx];
            A1l4[k][idx] = v1;
            d1 += v1.x * w.x + v1.y * w.y + v1.z * w.z + v1.w * w.w;
            const float4 v2 = r2[idx];
            A2l4[k][idx] = v2;
            d2 += v2.x * w.x + v2.y * w.y + v2.z * w.z + v2.w * w.w;
        }
#pragma unroll
        for (int m = 1; m <= 8; m <<= 1) {
            d1 += __shfl_xor(d1, m, 64);
            d2 += __shfl_xor(d2, m, 64);
        }
        if (t == 0) {
            wsS[b * LL + g * 16 + k]           = d1;
            wsS[BB * LL + b * LL + g * 16 + k] = d2;
        }
    }
    __threadfence();
    grid.sync();

    // ---- phase 2: softmax stats, one block per batch (g == 0) ----
    if (g == 0) {
        const int l1 = len1[b];
        const int l2 = len2[b];

        if (tid < LL) s1[tid]      = wsS[b * LL + tid];
        else          s2[tid - LL] = wsS[BB * LL + b * LL + (tid - LL)];
        __syncthreads();

        const int i2    = tid >> 1;
        const int jbase = (tid & 1) * 64;

        // global max over masked scores (2 threads per row)
        {
            float m = -1e7f;
            if (i2 < l1) {
                const float si = s1[i2];
                float m0 = -1e7f, m1 = -1e7f, m2 = -1e7f, m3 = -1e7f;
#pragma unroll 4
                for (int k = 0; k < 64; k += 4) {
                    const int j = jbase + k;
                    if (j + 0 < l2) m0 = fmaxf(m0, masked_we(si - s2[j + 0]));
                    if (j + 1 < l2) m1 = fmaxf(m1, masked_we(si - s2[j + 1]));
                    if (j + 2 < l2) m2 = fmaxf(m2, masked_we(si - s2[j + 2]));
                    if (j + 3 < l2) m3 = fmaxf(m3, masked_we(si - s2[j + 3]));
                }
                m = fmaxf(fmaxf(m0, m1), fmaxf(m2, m3));
            }
            m = waveReduceMax(m);
            if (lane == 0) redM[wave] = m;
        }
        __syncthreads();
        if (tid == 0)
            gmax_s = fmaxf(fmaxf(redM[0], redM[1]), fmaxf(redM[2], redM[3]));
        __syncthreads();
        const float gmax = gmax_s;

        // row partial sums (2 threads per row) + denominator
        {
            float acc = 0.f;
            if (i2 < l1) {
                const float si = s1[i2];
                for (int k = 0; k < 64; ++k) {
                    const int j = jbase + k;
                    if (j < l2) acc += expf(masked_we(si - s2[j]) - gmax);
                }
            }
            part[tid] = acc;
            const float wsum = waveReduceSum(acc);
            if (lane == 0) redS[wave] = wsum;
        }
        __syncthreads();
        if (tid < LL) rs[tid] = part[2 * tid] + part[2 * tid + 1];
        if (tid == 0) {
            float denom = redS[0] + redS[1] + redS[2] + redS[3];
            denom += (float)(LL * LL - l1 * l2) * expf(-1e7f - gmax);
            dinv_s = 1.0f / denom;
        }

        // col partial sums (2 threads per col)
        const int j2    = tid >> 1;
        const int ibase = (tid & 1) * 64;
        float acc2 = 0.f;
        if (j2 < l2) {
            const float sj = s2[j2];
            for (int k = 0; k < 64; ++k) {
                const int i = ibase + k;
                if (i < l1) acc2 += expf(masked_we(s1[i] - sj) - gmax);
            }
        }
        __syncthreads();
        part[tid] = acc2;
        __syncthreads();
        if (tid < LL) cs[tid] = part[2 * tid] + part[2 * tid + 1];
        __syncthreads();

        const float dinv = dinv_s;
        if (tid < LL) wsRC[b * 256 + tid] = rs[tid] * dinv;
        else          wsRC[b * 256 + tid] = cs[tid - LL] * dinv;
    }
    __threadfence();
    grid.sync();

    // ---- phase 3: partial pooled from LDS-cached rows ----
    {
        if (tid < 16)       rc1[tid]      = wsRC[b * 256 + g * 16 + tid];
        else if (tid < 32)  rc2[tid - 16] = wsRC[b * 256 + LL + g * 16 + (tid - 16)];
        __syncthreads();
        const float* __restrict__ A1s = (const float*)A1l4;
        const float* __restrict__ A2s = (const float*)A2l4;
        float p = 0.f;
#pragma unroll
        for (int k = 0; k < 16; ++k)
            p += rc1[k] * A1s[k * DD + tid] - rc2[k] * A2s[k * DD + tid];
        wsPp[(size_t)(b * 8 + g) * DD + tid] = p;
    }
    __threadfence();
    grid.sync();

    // ---- phase 4: sum pooled partials, FC + tanh (128 h per block) ----
    {
        float p = 0.f;
#pragma unroll
        for (int g2 = 0; g2 < 8; ++g2)
            p += wsPp[(size_t)(b * 8 + g2) * DD + tid];
        ps[tid] = p;
        __syncthreads();

        const int h    = g * 128 + (tid >> 1);
        const int half = tid & 1;
        const float4* __restrict__ wrow = (const float4*)(fcw + (size_t)h * DD) + half * 32;
        const float4* __restrict__ pp   = (const float4*)ps + half * 32;
        float ax = 0.f, ay = 0.f, az = 0.f, aw = 0.f;
#pragma unroll 8
        for (int q = 0; q < 32; ++q) {
            const float4 v = wrow[q];
            const float4 u = pp[q];
            ax += v.x * u.x; ay += v.y * u.y; az += v.z * u.z; aw += v.w * u.w;
        }
        float s = (ax + ay) + (az + aw);
        s += __shfl_xor(s, 1, 64);
        if (half == 0) out[(size_t)b * HH + h] = tanhf(s + fcb[h]);
    }
}

extern "C" void kernel_launch(void* const* d_in, const int* in_sizes, int n_in,
                              void* d_out, int out_size, void* d_ws, size_t ws_size,
                              hipStream_t stream) {
    const float* a1   = (const float*)d_in[0];
    const int*   len1 = (const int*)d_in[1];
    const float* a2   = (const float*)d_in[2];
    const int*   len2 = (const int*)d_in[3];
    const float* fcw  = (const float*)d_in[4];
    const float* fcb  = (const float*)d_in[5];
    const float* ww   = (const float*)d_in[6];
    float* out = (float*)d_out;

    float* wsS  = (float*)d_ws;        // 8192 floats
    float* wsRC = wsS + 8192;          // 8192 floats
    float* wsPp = wsRC + 8192;         // 65536 floats

    void* args[] = { (void*)&a1, (void*)&len1, (void*)&a2, (void*)&len2,
                     (void*)&fcw, (void*)&fcb, (void*)&ww, (void*)&out,
                     (void*)&wsS, (void*)&wsRC, (void*)&wsPp };
    hipLaunchCooperativeKernel((const void*)fused_all, dim3(256), dim3(256),
                               args, 0, stream);
}

// Round 5
// 27.037 us; speedup vs baseline: 5.9145x; 5.9145x over previous
//
#include <hip/hip_runtime.h>
#include <math.h>

#define BB 32
#define LL 128
#define DD 256
#define HH 1024   // 4*D

__device__ __forceinline__ float waveReduceSum(float v) {
#pragma unroll
    for (int m = 32; m >= 1; m >>= 1) v += __shfl_xor(v, m, 64);
    return v;
}
__device__ __forceinline__ float waveReduceMax(float v) {
#pragma unroll
    for (int m = 32; m >= 1; m >>= 1) v = fmaxf(v, __shfl_xor(v, m, 64));
    return v;
}

__device__ __forceinline__ float masked_we(float w) {
    return (fabsf(w) < 1e-7f) ? -1e7f : w;
}

// K_A: one block per batch, 1024 threads. s-dots -> stats -> pooled.
__global__ __launch_bounds__(1024) void batch_kernel(
    const float* __restrict__ a1, const int* __restrict__ len1,
    const float* __restrict__ a2, const int* __restrict__ len2,
    const float* __restrict__ ww, float* __restrict__ wsP)
{
    const int b    = blockIdx.x;
    const int tid  = threadIdx.x;
    const int wave = tid >> 6;     // 0..15
    const int lane = tid & 63;

    __shared__ __align__(16) float4 wws4[DD / 4];
    __shared__ float s1[LL], s2[LL], rsv[LL], csv[LL];
    __shared__ float part[1024];
    __shared__ float redM[16], redS[16];
    __shared__ float gmax_s, dinv_s;

    const int l1 = len1[b];
    const int l2 = len2[b];

    if (tid < DD / 4) wws4[tid] = ((const float4*)ww)[tid];
    __syncthreads();

    const float* __restrict__ A1 = a1 + (size_t)b * LL * DD;
    const float* __restrict__ A2 = a2 + (size_t)b * LL * DD;

    // ---- phase 1: 256 row-dots, 4 threads per row ----
    {
        const int r = tid >> 2;            // 0..255
        const int t = tid & 3;
        const float4* __restrict__ row = (const float4*)
            ((r < LL) ? (A1 + (size_t)r * DD) : (A2 + (size_t)(r - LL) * DD));
        float ax = 0.f, ay = 0.f, az = 0.f, aw = 0.f;
#pragma unroll
        for (int q = 0; q < 16; ++q) {
            const int idx = q * 4 + t;
            const float4 v = row[idx];
            const float4 w = wws4[idx];
            ax += v.x * w.x; ay += v.y * w.y; az += v.z * w.z; aw += v.w * w.w;
        }
        float s = (ax + ay) + (az + aw);
        s += __shfl_xor(s, 1, 64);
        s += __shfl_xor(s, 2, 64);
        if (t == 0) { if (r < LL) s1[r] = s; else s2[r - LL] = s; }
    }
    __syncthreads();

    const int i8  = tid >> 3;              // 0..127 (row or col)
    const int sub = tid & 7;               // stride-8 partner

    // ---- phase 2: global max over masked scores (8 threads/row, 16 each) ----
    {
        float m = -1e7f;                   // value of every invalid/masked entry
        if (i8 < l1) {
            const float si = s1[i8];
#pragma unroll
            for (int k = 0; k < 16; ++k) {
                const int j = sub + 8 * k;
                if (j < l2) m = fmaxf(m, masked_we(si - s2[j]));
            }
        }
        m = waveReduceMax(m);
        if (lane == 0) redM[wave] = m;
    }
    __syncthreads();
    if (tid == 0) {
        float m = redM[0];
#pragma unroll
        for (int w = 1; w < 16; ++w) m = fmaxf(m, redM[w]);
        gmax_s = m;
    }
    __syncthreads();
    const float gmax = gmax_s;

    // ---- phase 3a: row sums rs (8 threads/row) + denominator ----
    {
        float acc = 0.f;
        if (i8 < l1) {
            const float si = s1[i8];
#pragma unroll
            for (int k = 0; k < 16; ++k) {
                const int j = sub + 8 * k;
                if (j < l2) acc += expf(masked_we(si - s2[j]) - gmax);
            }
        }
        part[tid] = acc;
        const float wsum = waveReduceSum(acc);
        if (lane == 0) redS[wave] = wsum;
    }
    __syncthreads();
    if (tid < LL) {
        float r_ = 0.f;
#pragma unroll
        for (int q = 0; q < 8; ++q) r_ += part[tid * 8 + q];
        rsv[tid] = r_;
    }
    if (tid == 0) {
        float denom = 0.f;
#pragma unroll
        for (int w = 0; w < 16; ++w) denom += redS[w];
        denom += (float)(LL * LL - l1 * l2) * expf(-1e7f - gmax);
        dinv_s = 1.0f / denom;
    }

    // ---- phase 3b: col sums cs (8 threads/col) ----
    float acc2 = 0.f;
    if (i8 < l2) {
        const float sj = s2[i8];
#pragma unroll
        for (int k = 0; k < 16; ++k) {
            const int i = sub + 8 * k;
            if (i < l1) acc2 += expf(masked_we(s1[i] - sj) - gmax);
        }
    }
    __syncthreads();                       // rs readers done with part
    part[tid] = acc2;
    __syncthreads();
    if (tid < LL) {
        float c_ = 0.f;
#pragma unroll
        for (int q = 0; q < 8; ++q) c_ += part[tid * 8 + q];
        csv[tid] = c_;
    }
    __syncthreads();

    // ---- phase 4: pooled (a1/a2 re-read -> L2 hit), 4 row-groups x 256 d ----
    {
        const int d = tid & 255;
        const int g = tid >> 8;            // 0..3
        float p = 0.f;
#pragma unroll 8
        for (int k = 0; k < 32; ++k) {
            const int i = g * 32 + k;
            p += rsv[i] * A1[i * DD + d] - csv[i] * A2[i * DD + d];
        }
        part[tid] = p;
    }
    __syncthreads();
    if (tid < DD) {
        const float p = part[tid] + part[256 + tid] + part[512 + tid] + part[768 + tid];
        wsP[(size_t)b * DD + tid] = p * dinv_s;
    }
}

// K_B: out[b,h] = tanh(dot(pooled[b], fcw[h]) + fcb[h]); thread-per-output
__global__ __launch_bounds__(256) void fc_tanh_kernel(
    const float* __restrict__ wsP, const float* __restrict__ fcw,
    const float* __restrict__ fcb, float* __restrict__ out)
{
    const int c = blockIdx.x;      // h-chunk 0..3
    const int b = blockIdx.y;      // batch
    const int tid = threadIdx.x;

    __shared__ __align__(16) float4 ps4[DD / 4];
    if (tid < DD / 4) ps4[tid] = ((const float4*)(wsP + (size_t)b * DD))[tid];
    __syncthreads();

    const int h = c * 256 + tid;
    const float* __restrict__ wrow = fcw + (size_t)h * DD;
    float ax = 0.f, ay = 0.f, az = 0.f, aw = 0.f;
#pragma unroll 8
    for (int d = 0; d < DD / 4; ++d) {
        const float4 v = ((const float4*)wrow)[d];
        const float4 p = ps4[d];
        ax += v.x * p.x; ay += v.y * p.y; az += v.z * p.z; aw += v.w * p.w;
    }
    out[(size_t)b * HH + h] = tanhf((ax + ay) + (az + aw) + fcb[h]);
}

extern "C" void kernel_launch(void* const* d_in, const int* in_sizes, int n_in,
                              void* d_out, int out_size, void* d_ws, size_t ws_size,
                              hipStream_t stream) {
    const float* a1   = (const float*)d_in[0];
    const int*   len1 = (const int*)d_in[1];
    const float* a2   = (const float*)d_in[2];
    const int*   len2 = (const int*)d_in[3];
    const float* fcw  = (const float*)d_in[4];
    const float* fcb  = (const float*)d_in[5];
    const float* ww   = (const float*)d_in[6];
    float* out = (float*)d_out;
    float* wsP = (float*)d_ws;     // 32*256 floats

    batch_kernel<<<BB, 1024, 0, stream>>>(a1, len1, a2, len2, ww, wsP);
    fc_tanh_kernel<<<dim3(4, BB), 256, 0, stream>>>(wsP, fcw, fcb, out);
}